// Round 12
// baseline (217.335 us; speedup 1.0000x reference)
//
#include <hip/hip_runtime.h>
#include <hip/hip_bf16.h>

typedef __attribute__((ext_vector_type(4))) float f32x4;
typedef __attribute__((ext_vector_type(8))) short s16x8;
typedef __attribute__((ext_vector_type(4))) short s16x4;
using bf16 = __hip_bfloat16;

static constexpr int BB  = 4;
static constexpr int SQ  = 512;
static constexpr int SKV = 2048;
static constexpr int SKT = 512;
static constexpr int DIM = 1024;
static constexpr int NH  = 16;
static constexpr int HD  = 64;

#define MFMA32(A,B,C) __builtin_amdgcn_mfma_f32_16x16x32_bf16(A,B,C,0,0,0)

// device pass has the builtin; host pass gets a never-executed stub.
#if __has_builtin(__builtin_amdgcn_mfma_f32_16x16x16_bf16)
  #define MFMA16(A,B,C) __builtin_amdgcn_mfma_f32_16x16x16_bf16(A,B,C,0,0,0)
#elif __has_builtin(__builtin_amdgcn_mfma_f32_16x16x16bf16_1k)
  #define MFMA16(A,B,C) __builtin_amdgcn_mfma_f32_16x16x16bf16_1k(A,B,C,0,0,0)
#else
  #define MFMA16(A,B,C) (C)   // host-pass stub
#endif

#define SBAR() asm volatile("s_barrier" ::: "memory")

__device__ __forceinline__ float b2f(short s) {
  unsigned int u = ((unsigned int)(unsigned short)s) << 16;
  float f; __builtin_memcpy(&f, &u, 4); return f;
}
__device__ __forceinline__ short f2s(float f) {
  bf16 h = __float2bfloat16(f); short s; __builtin_memcpy(&s, &h, 2); return s;
}

__device__ __forceinline__ void gload16(const void* g, void* l) {
  __builtin_amdgcn_global_load_lds(
      (const __attribute__((address_space(1))) void*)g,
      (__attribute__((address_space(3))) void*)l, 16, 0, 0);
}

static constexpr float QSCALE = 0.180336880111120426f;  // 0.125 * log2(e)

// --------- merged prep: weight cast f32->bf16  +  RMSNorm (one launch) ------
struct PrepArgs {
  const float* csrc[10]; bf16* cdst[10]; int cn[10];
  const float* nx[3]; const float* nw[3]; bf16* ny[3];
};
__global__ __launch_bounds__(256) void prep_kernel(PrepArgs a) {
  const int bx = blockIdx.x;
  if (bx < 10240) {
    const int y = bx >> 10;
    const int i = ((bx & 1023) * 256 + threadIdx.x) * 4;
    if (i >= a.cn[y]) return;
    const float4 v = *(const float4*)(a.csrc[y] + i);
    bf16* d = a.cdst[y] + i;
    d[0] = __float2bfloat16(v.x); d[1] = __float2bfloat16(v.y);
    d[2] = __float2bfloat16(v.z); d[3] = __float2bfloat16(v.w);
    return;
  }
  const int j = bx - 10240;
  int t, row;
  if (j < 2048) { t = 0; row = j; }
  else if (j < 10240) { t = 1; row = j - 2048; }
  else { t = 2; row = j - 10240; }
  const float* x = a.nx[t] + (size_t)row * DIM;
  const float4 v = *(const float4*)(x + threadIdx.x * 4);
  float ss = v.x*v.x + v.y*v.y + v.z*v.z + v.w*v.w;
  #pragma unroll
  for (int m = 32; m >= 1; m >>= 1) ss += __shfl_xor(ss, m);
  __shared__ float red[4];
  if ((threadIdx.x & 63) == 0) red[threadIdx.x >> 6] = ss;
  __syncthreads();
  ss = red[0] + red[1] + red[2] + red[3];
  const float sc = rsqrtf(ss * (1.0f / DIM) + 1.1920928955078125e-07f);
  const float4 w = *(const float4*)(a.nw[t] + threadIdx.x * 4);
  bf16* y = a.ny[t] + (size_t)row * DIM + threadIdx.x * 4;
  y[0] = __float2bfloat16(v.x * sc * w.x);
  y[1] = __float2bfloat16(v.y * sc * w.y);
  y[2] = __float2bfloat16(v.z * sc * w.z);
  y[3] = __float2bfloat16(v.w * sc * w.w);
}

// ============== 256x256 8-wave pipelined projection GEMM (r9 frozen) =========
struct PSlot { const bf16* A; const bf16* W; const float* bias;
               bf16* Cb; int epi; int sksh; };
struct PArgs { PSlot s[7]; };

__global__ __launch_bounds__(512, 2) void proj256(PArgs a) {
  __shared__ char lds[131072];   // [buf][A 32KB | B 32KB]
  const int tid = threadIdx.x, lane = tid & 63, wave = tid >> 6;
  const int m16 = lane & 15, g16 = lane >> 4;
  const int wm = wave >> 2, wn = wave & 3;

  const int i = (blockIdx.x & 7) * 64 + (blockIdx.x >> 3);
  int slot, rem;
  if (i < 384) { slot = i >> 7; rem = i & 127; }
  else { const int j = i - 384; slot = 3 + (j >> 5); rem = j & 31; }
  const PSlot S = a.s[slot];
  const int bn = rem & 3, bm = rem >> 2;

  const bf16* Ab = S.A + (size_t)bm * 256 * DIM;
  const bf16* Wb = S.W + (size_t)bn * 256 * DIM;

  auto stageAh = [&](int k0, int buf, int h) {
    #pragma unroll
    for (int q = 0; q < 2; ++q) {
      const int idx = (h * 2 + q) * 512 + tid;
      const int row = idx >> 3, g = (idx & 7) ^ (row & 7);
      gload16(Ab + (size_t)row * DIM + k0 + g * 8,
              &lds[buf * 65536 + (h * 2 + q) * 8192 + wave * 1024]);
    }
  };
  auto stageBfull = [&](int k0, int buf) {
    #pragma unroll
    for (int q = 0; q < 4; ++q) {
      const int idx = q * 512 + tid;
      const int row = idx >> 3, g = (idx & 7) ^ (row & 7);
      gload16(Wb + (size_t)row * DIM + k0 + g * 8,
              &lds[buf * 65536 + 32768 + q * 8192 + wave * 1024]);
    }
  };

  f32x4 acc[8][4];
  #pragma unroll
  for (int x = 0; x < 8; ++x)
    #pragma unroll
    for (int y = 0; y < 4; ++y)
      #pragma unroll
      for (int r = 0; r < 4; ++r) acc[x][y][r] = 0.0f;

  stageAh(0, 0, 0); stageAh(0, 0, 1);
  stageBfull(0, 0);
  stageBfull(64, 1);
  asm volatile("s_waitcnt vmcnt(4)" ::: "memory");
  SBAR();

  constexpr int NT = DIM / 64;   // 16
  for (int t = 0; t < NT; ++t) {
    const int buf = t & 1;
    const char* A0 = &lds[buf * 65536];
    const char* B0 = A0 + 32768;
    s16x8 af[4], bfk[4];

    // ---- P0: ds af(mh0,ks0) 4 + bf(ks0) 4; stage A(t+1) h0 ----
    #pragma unroll
    for (int mi = 0; mi < 4; ++mi) {
      const int row = wm * 128 + mi * 16 + m16;
      af[mi] = *(const s16x8*)(A0 + row * 128 + ((g16 ^ (m16 & 7)) * 16));
    }
    #pragma unroll
    for (int ni = 0; ni < 4; ++ni) {
      const int row = wn * 64 + ni * 16 + m16;
      bfk[ni] = *(const s16x8*)(B0 + row * 128 + ((g16 ^ (m16 & 7)) * 16));
    }
    if (t + 1 < NT) stageAh((t + 1) * 64, buf ^ 1, 0);
    SBAR();
    __builtin_amdgcn_s_setprio(1);
    #pragma unroll
    for (int mi = 0; mi < 4; ++mi)
      #pragma unroll
      for (int ni = 0; ni < 4; ++ni)
        acc[mi][ni] = MFMA32(af[mi], bfk[ni], acc[mi][ni]);
    __builtin_amdgcn_s_setprio(0);
    SBAR();

    // ---- P1: ds af(mh1,ks0) 4; stage A(t+1) h1 ----
    #pragma unroll
    for (int mi = 0; mi < 4; ++mi) {
      const int row = wm * 128 + 64 + mi * 16 + m16;
      af[mi] = *(const s16x8*)(A0 + row * 128 + ((g16 ^ (m16 & 7)) * 16));
    }
    if (t + 1 < NT) stageAh((t + 1) * 64, buf ^ 1, 1);
    SBAR();
    __builtin_amdgcn_s_setprio(1);
    #pragma unroll
    for (int mi = 0; mi < 4; ++mi)
      #pragma unroll
      for (int ni = 0; ni < 4; ++ni)
        acc[4 + mi][ni] = MFMA32(af[mi], bfk[ni], acc[4 + mi][ni]);
    __builtin_amdgcn_s_setprio(0);
    SBAR();

    // ---- P2: ds af(mh0,ks1) 4 + bf(ks1) 4 ----
    #pragma unroll
    for (int mi = 0; mi < 4; ++mi) {
      const int row = wm * 128 + mi * 16 + m16;
      af[mi] = *(const s16x8*)(A0 + row * 128 + (((4 + g16) ^ (m16 & 7)) * 16));
    }
    #pragma unroll
    for (int ni = 0; ni < 4; ++ni) {
      const int row = wn * 64 + ni * 16 + m16;
      bfk[ni] = *(const s16x8*)(B0 + row * 128 + (((4 + g16) ^ (m16 & 7)) * 16));
    }
    SBAR();
    __builtin_amdgcn_s_setprio(1);
    #pragma unroll
    for (int mi = 0; mi < 4; ++mi)
      #pragma unroll
      for (int ni = 0; ni < 4; ++ni)
        acc[mi][ni] = MFMA32(af[mi], bfk[ni], acc[mi][ni]);
    __builtin_amdgcn_s_setprio(0);
    SBAR();

    // ---- P3: ds af(mh1,ks1) 4; stage B(t+2) ----
    #pragma unroll
    for (int mi = 0; mi < 4; ++mi) {
      const int row = wm * 128 + 64 + mi * 16 + m16;
      af[mi] = *(const s16x8*)(A0 + row * 128 + (((4 + g16) ^ (m16 & 7)) * 16));
    }
    if (t + 2 < NT) stageBfull((t + 2) * 64, buf);
    SBAR();
    __builtin_amdgcn_s_setprio(1);
    #pragma unroll
    for (int mi = 0; mi < 4; ++mi)
      #pragma unroll
      for (int ni = 0; ni < 4; ++ni)
        acc[4 + mi][ni] = MFMA32(af[mi], bfk[ni], acc[4 + mi][ni]);
    __builtin_amdgcn_s_setprio(0);
    if (t < NT - 2)       { asm volatile("s_waitcnt vmcnt(4)" ::: "memory"); }
    else if (t == NT - 2) { asm volatile("s_waitcnt vmcnt(0)" ::: "memory"); }
    SBAR();
  }

  const int r0 = bm * 256 + wm * 128, c0 = bn * 256 + wn * 64;
  if (S.epi >= 3) {
    const float sc = (S.epi == 3) ? QSCALE : 1.0f;
    const int msk = (1 << S.sksh) - 1;
    #pragma unroll
    for (int ng = 0; ng < 4; ++ng) {
      const int col = c0 + ng * 16 + m16;
      const int hh = col >> 6, d = col & 63;
      const float bv = S.bias[col];
      #pragma unroll
      for (int mg = 0; mg < 8; ++mg) {
        const int rowb = r0 + mg * 16 + g16 * 4;
        #pragma unroll
        for (int r = 0; r < 4; ++r) {
          const int m = rowb + r;
          const int bb2 = m >> S.sksh, tok = m & msk;
          S.Cb[(((size_t)(bb2 * NH + hh) << S.sksh) + tok) * HD + d] =
              __float2bfloat16((acc[mg][ng][r] + bv) * sc);
        }
      }
    }
  } else {
    #pragma unroll
    for (int ng = 0; ng < 4; ++ng) {
      const int col = c0 + ng * 16 + m16;
      const float bv = S.bias[col];
      #pragma unroll
      for (int mg = 0; mg < 8; ++mg) {
        const int rowb = r0 + mg * 16 + g16 * 4;
        #pragma unroll
        for (int r = 0; r < 4; ++r) {
          float v = acc[mg][ng][r] + bv;
          const size_t idx = (size_t)(rowb + r) * DIM + col;
          if (S.epi == 1) { v = v / (1.0f + __expf(-v)); S.Cb[idx] = __float2bfloat16(v); }
          else            { S.Cb[idx] = __float2bfloat16(v); }
        }
      }
    }
  }
}

// -------- out-projection GEMM: 64x128 tile, 256 blocks (full CU fill) --------
struct GSlot { const bf16* A; const bf16* W; const float* bias;
               const float* resid; float* Cf; };
__global__ __launch_bounds__(256) void gemm_out(GSlot S) {
  constexpr int K = DIM;
  __shared__ alignas(16) char sA[4096];
  __shared__ alignas(16) char sB[8192];
  const int tid = threadIdx.x, lane = tid & 63, wave = tid >> 6;
  const int bm = blockIdx.x, bn = blockIdx.y;
  const int m16 = lane & 15, g16 = lane >> 4;

  f32x4 acc[4][2];
  #pragma unroll
  for (int i = 0; i < 4; ++i)
    #pragma unroll
    for (int j = 0; j < 2; ++j)
      #pragma unroll
      for (int r = 0; r < 4; ++r) acc[i][j][r] = 0.0f;

  const bf16* Ab = S.A + (size_t)bm * 64 * K;
  const bf16* Wb = S.W + (size_t)bn * 128 * K;

  for (int t = 0; t < K / 32; ++t) {
    const int k0 = t * 32;
    {
      const int row = tid >> 2, sg = (tid & 3) ^ (row & 3);
      gload16(Ab + (size_t)row * K + k0 + sg * 8, &sA[wave * 1024]);
    }
    #pragma unroll
    for (int p = 0; p < 2; ++p) {
      const int idx = p * 256 + tid;
      const int row = idx >> 2, sg = (idx & 3) ^ (row & 3);
      gload16(Wb + (size_t)row * K + k0 + sg * 8, &sB[p * 4096 + wave * 1024]);
    }
    __syncthreads();
    s16x8 af[4], bfr[2];
    #pragma unroll
    for (int mi = 0; mi < 4; ++mi) {
      const int row = mi * 16 + m16;
      af[mi] = *(const s16x8*)(&sA[row * 64 + (g16 ^ (m16 & 3)) * 16]);
    }
    #pragma unroll
    for (int ni = 0; ni < 2; ++ni) {
      const int row = wave * 32 + ni * 16 + m16;
      bfr[ni] = *(const s16x8*)(&sB[row * 64 + (g16 ^ (m16 & 3)) * 16]);
    }
    #pragma unroll
    for (int mi = 0; mi < 4; ++mi)
      #pragma unroll
      for (int ni = 0; ni < 2; ++ni)
        acc[mi][ni] = MFMA32(af[mi], bfr[ni], acc[mi][ni]);
    __syncthreads();
  }

  const int r0 = bm * 64, c0 = bn * 128 + wave * 32;
  #pragma unroll
  for (int ni = 0; ni < 2; ++ni) {
    const int col = c0 + ni * 16 + m16;
    const float bv = S.bias[col];
    #pragma unroll
    for (int mi = 0; mi < 4; ++mi) {
      const int rowb = r0 + mi * 16 + g16 * 4;
      #pragma unroll
      for (int r = 0; r < 4; ++r) {
        const size_t idx = (size_t)(rowb + r) * DIM + col;
        S.Cf[idx] = acc[mi][ni][r] + bv + S.resid[idx];
      }
    }
  }
}

// ---------------- merged gate GEMV (visual + text) ---------------------------
__global__ __launch_bounds__(256) void gate2_kernel(
    const bf16* __restrict__ g1v, const bf16* __restrict__ w2v,
    const float* __restrict__ b2v, float* __restrict__ gv,
    const bf16* __restrict__ g1t, const bf16* __restrict__ w2t,
    const float* __restrict__ b2t, float* __restrict__ gt)
{
  const int lane = threadIdx.x & 63, wave = threadIdx.x >> 6;
  int row = blockIdx.x * 4 + wave;
  const bf16* x; const bf16* w2; const float* b2; float* gate;
  if (row < BB * SKV) { x = g1v + (size_t)row * DIM; w2 = w2v; b2 = b2v; gate = gv + row; }
  else { row -= BB * SKV; x = g1t + (size_t)row * DIM; w2 = w2t; b2 = b2t; gate = gt + row; }
  float sum = 0.0f;
  #pragma unroll
  for (int c = 0; c < 2; ++c) {
    const int i0 = c * 512 + lane * 8;
    const s16x8 xv = *(const s16x8*)(x + i0);
    const s16x8 wv = *(const s16x8*)(w2 + i0);
    #pragma unroll
    for (int j = 0; j < 8; ++j) sum += b2f(xv[j]) * b2f(wv[j]);
  }
  #pragma unroll
  for (int m = 32; m >= 1; m >>= 1) sum += __shfl_xor(sum, m);
  if (lane == 0) *gate = 1.0f / (1.0f + __expf(-(sum + b2[0])));
}

// ------- merged V transpose + gate fold --------------------------------------
__global__ __launch_bounds__(256) void vtrans2_kernel(
    const bf16* __restrict__ Vv, const float* __restrict__ gv, bf16* __restrict__ VTv,
    const bf16* __restrict__ Vt, const float* __restrict__ gt, bf16* __restrict__ VTt)
{
  __shared__ alignas(16) short tile[64][72];
  int kt = blockIdx.x;
  const bf16* V; const float* gate; bf16* VT; int Sk;
  if (kt < SKV / 64) { V = Vv; gate = gv; VT = VTv; Sk = SKV; }
  else { kt -= SKV / 64; V = Vt; gate = gt; VT = VTt; Sk = SKT; }
  const int h = blockIdx.y, b = blockIdx.z;
  const int tid = threadIdx.x;
  #pragma unroll
  for (int i = 0; i < 2; ++i) {
    const int c = tid + i * 256;
    const int kr = c >> 3, d0 = (c & 7) * 8;
    const float g = gate[(size_t)b * Sk + kt * 64 + kr];
    const s16x8 v = *(const s16x8*)(V + ((size_t)(b*Sk + kt*64 + kr)*NH + h)*HD + d0);
    #pragma unroll
    for (int j = 0; j < 8; ++j) tile[kr][d0 + j] = f2s(b2f(v[j]) * g);
  }
  __syncthreads();
  #pragma unroll
  for (int i = 0; i < 2; ++i) {
    const int c = tid + i * 256;
    const int d = c >> 3, k0 = (c & 7) * 8;
    s16x8 v;
    #pragma unroll
    for (int j = 0; j < 8; ++j) v[j] = tile[k0 + j][d];
    *(s16x8*)(VT + ((size_t)(b*NH + h)*HD + d)*Sk + kt*64 + k0) = v;
  }
}

// ---------------- fused dual-context flash attention -------------------------
// r9 structure (8 waves, hf-split, 128-wide chunks) with ONE change:
// 3-buffer rotation + counted vmcnt(4) instead of vmcnt(0) drain per chunk.
// Each stage = 4 gload_lds; next chunk's loads stay in flight across barriers.
__global__ __launch_bounds__(512, 2) void attn_kernel(
    const bf16* __restrict__ Qh,
    const bf16* __restrict__ K1h, const bf16* __restrict__ VT1,
    const bf16* __restrict__ K2h, const bf16* __restrict__ VT2,
    bf16* __restrict__ Hout)
{
  __shared__ alignas(16) char sK[3][2][8192];   // [buf][half][64 tok x 64 d]
  __shared__ alignas(16) char sVT[3][2][8192];  // [buf][half][64 d x 64 kv]
  const int tid = threadIdx.x, lane = tid & 63, wave = tid >> 6;
  const int hb = blockIdx.x;
  const int h = hb & 15, b = hb >> 4;
  const int wq = wave & 3, hf = wave >> 2;
  const int q0 = blockIdx.y * 64 + wq * 16;
  const int m16 = lane & 15, g16 = lane >> 4;

  const bf16* qrow = Qh + ((size_t)(b*NH + h)*SQ + q0 + m16)*HD;
  const s16x8 qf0 = *(const s16x8*)(qrow + g16 * 8);
  const s16x8 qf1 = *(const s16x8*)(qrow + 32 + g16 * 8);

  const bf16* K1b  = K1h + (size_t)(b*NH + h) * SKV * HD;
  const bf16* K2b  = K2h + (size_t)(b*NH + h) * SKT * HD;
  const bf16* VT1b = VT1 + (size_t)(b*NH + h) * HD * SKV;
  const bf16* VT2b = VT2 + (size_t)(b*NH + h) * HD * SKT;

  constexpr int NC1 = SKV / 128, NC = NC1 + SKT / 128;  // 16 + 4

  // stage chunk c into buf: 4 gload16/thread (K h0/h1, VT h0/h1)
  auto stage = [&](int c, int buf) {
    const int ctx = (c >= NC1);
    const bf16* Kb  = ctx ? K2b  : K1b;
    const bf16* VTb = ctx ? VT2b : VT1b;
    const int Sk = ctx ? SKT : SKV;
    const int cc = ctx ? c - NC1 : c;
    const int b0 = cc * 64, b1 = (Sk >> 1) + cc * 64;
    const int r = tid >> 3, g = (tid & 7) ^ (r & 7);
    gload16(Kb  + (size_t)(b0 + r) * HD + g * 8, &sK[buf][0][wave * 1024]);
    gload16(Kb  + (size_t)(b1 + r) * HD + g * 8, &sK[buf][1][wave * 1024]);
    gload16(VTb + (size_t)r * Sk + b0 + g * 8,   &sVT[buf][0][wave * 1024]);
    gload16(VTb + (size_t)r * Sk + b1 + g * 8,   &sVT[buf][1][wave * 1024]);
  };

  f32x4 o[4], ov[4];
  float mx, l, mxv, lv;
  #pragma unroll
  for (int i = 0; i < 4; ++i)
    #pragma unroll
    for (int r = 0; r < 4; ++r) { o[i][r] = 0.0f; ov[i][r] = 0.0f; }
  mx = -1e30f; l = 0.0f; mxv = -1e30f; lv = 0.0f;

  auto chunk = [&](int buf) {
    const char* kbase = &sK[buf][hf][0];
    const char* vbase = &sVT[buf][hf][0];
    f32x4 s[4];
    #pragma unroll
    for (int nt = 0; nt < 4; ++nt) {
      const char* kr = kbase + (nt * 16 + m16) * 128;
      const s16x8 kf0 = *(const s16x8*)(kr + ((g16    ) ^ (m16 & 7)) * 16);
      const s16x8 kf1 = *(const s16x8*)(kr + ((4 + g16) ^ (m16 & 7)) * 16);
      f32x4 a2; a2[0] = 0; a2[1] = 0; a2[2] = 0; a2[3] = 0;
      a2 = MFMA32(kf0, qf0, a2);
      a2 = MFMA32(kf1, qf1, a2);
      s[nt] = a2;
    }
    float mc = s[0][0];
    #pragma unroll
    for (int nt = 0; nt < 4; ++nt)
      #pragma unroll
      for (int r = 0; r < 4; ++r) mc = fmaxf(mc, s[nt][r]);
    mc = fmaxf(mc, __shfl_xor(mc, 16));
    mc = fmaxf(mc, __shfl_xor(mc, 32));
    const float mnew = fmaxf(mx, mc);
    const float alpha = exp2f(mx - mnew);
    mx = mnew;
    float p[4][4]; float rs = 0.0f;
    #pragma unroll
    for (int nt = 0; nt < 4; ++nt)
      #pragma unroll
      for (int r = 0; r < 4; ++r) { p[nt][r] = exp2f(s[nt][r] - mnew); rs += p[nt][r]; }
    rs += __shfl_xor(rs, 16);
    rs += __shfl_xor(rs, 32);
    l = l * alpha + rs;
    float av[4];
    #pragma unroll
    for (int r = 0; r < 4; ++r) av[r] = __shfl(alpha, g16 * 4 + r);
    #pragma unroll
    for (int nd = 0; nd < 4; ++nd)
      #pragma unroll
      for (int r = 0; r < 4; ++r) o[nd][r] *= av[r];
    #pragma unroll
    for (int nt = 0; nt < 4; ++nt) {
      s16x4 pa;
      pa[0] = f2s(p[nt][0]); pa[1] = f2s(p[nt][1]);
      pa[2] = f2s(p[nt][2]); pa[3] = f2s(p[nt][3]);
      #pragma unroll
      for (int nd = 0; nd < 4; ++nd) {
        const int d = nd * 16 + m16;
        const int g = (nt * 2 + (g16 >> 1)) ^ (m16 & 7);
        const s16x4 vf = *(const s16x4*)(vbase + d * 128 + g * 16 + (g16 & 1) * 8);
        o[nd] = MFMA16(pa, vf, o[nd]);
      }
    }
  };

  // prologue: stage chunks 0,1; wait for 0 only (1's 4 loads stay in flight)
  stage(0, 0);
  stage(1, 1);
  asm volatile("s_waitcnt vmcnt(4)" ::: "memory");
  SBAR();

  for (int c = 0; c < NC; ++c) {
    if (c + 2 < NC) stage(c + 2, (c + 2) % 3);
    chunk(c % 3);
    if (c == NC1 - 1) {   // save visual-context state, reset for text
      #pragma unroll
      for (int nd = 0; nd < 4; ++nd) ov[nd] = o[nd];
      mxv = mx; lv = l;
      #pragma unroll
      for (int nd = 0; nd < 4; ++nd)
        #pragma unroll
        for (int r = 0; r < 4; ++r) o[nd][r] = 0.0f;
      mx = -1e30f; l = 0.0f;
    }
    // counted wait: stage(c+1) landed; stage(c+2)'s 4 loads stay in flight
    if (c + 2 < NC) { asm volatile("s_waitcnt vmcnt(4)" ::: "memory"); }
    else            { asm volatile("s_waitcnt vmcnt(0)" ::: "memory"); }
    SBAR();
  }

  // ---- final merges (LDS free now). scratch: mo[ctx][64 rows][64 d] -------
  float* mo = (float*)&sK[0][0][0];    // 2 x 16KB = 32KB
  float* ml = (float*)&sVT[0][0][0];   // [wq][ctx][2][16]
  if (hf) {
    #pragma unroll
    for (int nd = 0; nd < 4; ++nd)
      #pragma unroll
      for (int r = 0; r < 4; ++r) {
        const int rl = wq * 16 + g16 * 4 + r;
        mo[rl * 64 + nd * 16 + m16]        = ov[nd][r];
        mo[4096 + rl * 64 + nd * 16 + m16] = o[nd][r];
      }
    if (g16 == 0) {
      ml[(wq * 4 + 0) * 16 + m16] = mxv; ml[(wq * 4 + 1) * 16 + m16] = lv;
      ml[(wq * 4 + 2) * 16 + m16] = mx;  ml[(wq * 4 + 3) * 16 + m16] = l;
    }
  }
  __syncthreads();
  if (!hf) {
    float of[4][4];
    #pragma unroll
    for (int ctx = 0; ctx < 2; ++ctx) {
      const float mb = ml[(wq * 4 + ctx * 2 + 0) * 16 + m16];
      const float lb = ml[(wq * 4 + ctx * 2 + 1) * 16 + m16];
      const float ma = ctx ? mx : mxv;
      const float la = ctx ? l  : lv;
      const float ms = fmaxf(ma, mb);
      const float aA = exp2f(ma - ms), aB = exp2f(mb - ms);
      const float lt = la * aA + lb * aB;
      float aAv[4], aBv[4], ltv[4];
      #pragma unroll
      for (int r = 0; r < 4; ++r) {
        aAv[r] = __shfl(aA, g16 * 4 + r);
        aBv[r] = __shfl(aB, g16 * 4 + r);
        ltv[r] = __shfl(lt, g16 * 4 + r);
      }
      #pragma unroll
      for (int nd = 0; nd < 4; ++nd)
        #pragma unroll
        for (int r = 0; r < 4; ++r) {
          const int rl = wq * 16 + g16 * 4 + r;
          const float ob = mo[ctx * 4096 + rl * 64 + nd * 16 + m16];
          const float oa = ctx ? o[nd][r] : ov[nd][r];
          const float res = (oa * aAv[r] + ob * aBv[r]) / ltv[r];
          if (ctx == 0) of[nd][r] = res; else of[nd][r] += res;
        }
    }
    #pragma unroll
    for (int nd = 0; nd < 4; ++nd)
      #pragma unroll
      for (int r = 0; r < 4; ++r) {
        const int row = q0 + g16 * 4 + r;
        Hout[((size_t)(b*SQ + row)*NH + h)*HD + nd*16 + m16] =
            __float2bfloat16(of[nd][r]);
      }
  }
}

// ---------------- host launch ------------------------------------------------
extern "C" void kernel_launch(void* const* d_in, const int* in_sizes, int n_in,
                              void* d_out, int out_size, void* d_ws, size_t ws_size,
                              hipStream_t stream)
{
  const float* queries = (const float*)d_in[0];
  const float* ctx_v   = (const float*)d_in[1];
  const float* ctx_t   = (const float*)d_in[2];
  const float* w_nq = (const float*)d_in[3];
  const float* w_nv = (const float*)d_in[4];
  const float* w_nt = (const float*)d_in[5];
  const float* Wq   = (const float*)d_in[6];  const float* bq   = (const float*)d_in[7];
  const float* Wk_v = (const float*)d_in[8];  const float* bk_v = (const float*)d_in[9];
  const float* Wv_v = (const float*)d_in[10]; const float* bv_v = (const float*)d_in[11];
  const float* Wk_t = (const float*)d_in[12]; const float* bk_t = (const float*)d_in[13];
  const float* Wv_t = (const float*)d_in[14]; const float* bv_t = (const float*)d_in[15];
  const float* Wg1v = (const float*)d_in[16]; const float* bg1v = (const float*)d_in[17];
  const float* Wg2v = (const float*)d_in[18]; const float* bg2v = (const float*)d_in[19];
  const float* Wg1t = (const float*)d_in[20]; const float* bg1t = (const float*)d_in[21];
  const float* Wg2t = (const float*)d_in[22]; const float* bg2t = (const float*)d_in[23];
  const float* Wo   = (const float*)d_in[24]; const float* bo   = (const float*)d_in[25];

  char* ws = (char*)d_ws;
  size_t off = 0;
  auto alloc = [&](size_t n) { void* p = ws + off; off += (n + 255) & ~(size_t)255; return p; };

  const size_t MATB = (size_t)DIM * DIM * 2;
  bf16* WqB   = (bf16*)alloc(MATB);
  bf16* WkvB  = (bf16*)alloc(MATB);
  bf16* WvvB  = (bf16*)alloc(MATB);
  bf16* WktB  = (bf16*)alloc(MATB);
  bf16* WvtB  = (bf16*)alloc(MATB);
  bf16* Wg1vB = (bf16*)alloc(MATB);
  bf16* Wg1tB = (bf16*)alloc(MATB);
  bf16* WoB   = (bf16*)alloc(MATB);
  bf16* Wg2vB = (bf16*)alloc(2048);
  bf16* Wg2tB = (bf16*)alloc(2048);

  bf16* qn  = (bf16*)alloc((size_t)BB*SQ*DIM*2);
  bf16* cv  = (bf16*)alloc((size_t)BB*SKV*DIM*2);
  bf16* ct  = (bf16*)alloc((size_t)BB*SKT*DIM*2);
  bf16* qb  = (bf16*)alloc((size_t)BB*SQ*DIM*2);     // head-major, scaled
  bf16* kvB = (bf16*)alloc((size_t)BB*SKV*DIM*2);    // head-major
  bf16* ktB = (bf16*)alloc((size_t)BB*SKT*DIM*2);    // head-major
  bf16* vtV = (bf16*)alloc((size_t)BB*SKV*DIM*2);
  bf16* vtT = (bf16*)alloc((size_t)BB*SKT*DIM*2);
  bf16* vScrV = (bf16*)alloc((size_t)BB*SKV*DIM*2);
  bf16* vScrT = (bf16*)alloc((size_t)BB*SKT*DIM*2);
  bf16* g1V   = (bf16*)alloc((size_t)BB*SKV*DIM*2);
  bf16* g1T   = (bf16*)alloc((size_t)BB*SKT*DIM*2);
  float* gateV = (float*)alloc((size_t)BB*SKV*4);
  float* gateT = (float*)alloc((size_t)BB*SKT*4);
  bf16* hB  = (bf16*)alloc((size_t)BB*SQ*DIM*2);
  (void)ws_size; (void)n_in; (void)in_sizes; (void)out_size;

  // 1. weight casts + RMSNorms in ONE launch
  PrepArgs pr;
  const float* wsrc[10] = {Wq, Wk_v, Wv_v, Wk_t, Wv_t, Wg1v, Wg1t, Wo, Wg2v, Wg2t};
  bf16* wdst[10] = {WqB, WkvB, WvvB, WktB, WvtB, Wg1vB, Wg1tB, WoB, Wg2vB, Wg2tB};
  for (int i = 0; i < 10; ++i) {
    pr.csrc[i] = wsrc[i]; pr.cdst[i] = wdst[i];
    pr.cn[i] = (i < 8) ? DIM * DIM : DIM;
  }
  pr.nx[0] = queries; pr.nx[1] = ctx_v; pr.nx[2] = ctx_t;
  pr.nw[0] = w_nq;    pr.nw[1] = w_nv;  pr.nw[2] = w_nt;
  pr.ny[0] = qn;      pr.ny[1] = cv;    pr.ny[2] = ct;
  prep_kernel<<<dim3(10240 + 12288), 256, 0, stream>>>(pr);

  // 2. ALL 7 projections in one 256^2 pipelined dispatch
  PArgs pa;
  pa.s[0] = {cv, WkvB,  bk_v, kvB,   4, 11};   // K visual, head-major
  pa.s[1] = {cv, WvvB,  bv_v, vScrV, 0, 0};    // V visual
  pa.s[2] = {cv, Wg1vB, bg1v, g1V,   1, 0};    // G1 visual (silu)
  pa.s[3] = {qn, WqB,   bq,   qb,    3, 9};    // Q, head-major + scale
  pa.s[4] = {ct, WktB,  bk_t, ktB,   4, 9};    // K text, head-major
  pa.s[5] = {ct, WvtB,  bv_t, vScrT, 0, 0};    // V text
  pa.s[6] = {ct, Wg1tB, bg1t, g1T,   1, 0};    // G1 text (silu)
  proj256<<<dim3(512), 512, 0, stream>>>(pa);

  // 3. gates (both contexts) + gated V transpose (both contexts)
  gate2_kernel<<<dim3((BB*SKV + BB*SKT) / 4), 256, 0, stream>>>(
      g1V, Wg2vB, bg2v, gateV, g1T, Wg2tB, bg2t, gateT);
  vtrans2_kernel<<<dim3(SKV/64 + SKT/64, NH, BB), 256, 0, stream>>>(
      vScrV, gateV, vtV, vScrT, gateT, vtT);

  // 4. fused dual-context attention (r9 structure + 3-buf counted vmcnt)
  attn_kernel<<<dim3(NH*BB, SQ/64), 512, 0, stream>>>(qb, kvB, vtV, ktB, vtT, hB);

  // 5. output projection + residual (f32 out), 256 blocks
  GSlot go{hB, WoB, bo, queries, (float*)d_out};
  gemm_out<<<dim3(BB*SQ/64, 8), 256, 0, stream>>>(go);
}

// Round 13
// 195.640 us; speedup vs baseline: 1.1109x; 1.1109x over previous
//
#include <hip/hip_runtime.h>
#include <hip/hip_bf16.h>

typedef __attribute__((ext_vector_type(4))) float f32x4;
typedef __attribute__((ext_vector_type(8))) short s16x8;
typedef __attribute__((ext_vector_type(4))) short s16x4;
using bf16 = __hip_bfloat16;

static constexpr int BB  = 4;
static constexpr int SQ  = 512;
static constexpr int SKV = 2048;
static constexpr int SKT = 512;
static constexpr int DIM = 1024;
static constexpr int NH  = 16;
static constexpr int HD  = 64;

#define MFMA32(A,B,C) __builtin_amdgcn_mfma_f32_16x16x32_bf16(A,B,C,0,0,0)

// device pass has the builtin; host pass gets a never-executed stub.
#if __has_builtin(__builtin_amdgcn_mfma_f32_16x16x16_bf16)
  #define MFMA16(A,B,C) __builtin_amdgcn_mfma_f32_16x16x16_bf16(A,B,C,0,0,0)
#elif __has_builtin(__builtin_amdgcn_mfma_f32_16x16x16bf16_1k)
  #define MFMA16(A,B,C) __builtin_amdgcn_mfma_f32_16x16x16bf16_1k(A,B,C,0,0,0)
#else
  #define MFMA16(A,B,C) (C)   // host-pass stub
#endif

#define SBAR() asm volatile("s_barrier" ::: "memory")

__device__ __forceinline__ float b2f(short s) {
  unsigned int u = ((unsigned int)(unsigned short)s) << 16;
  float f; __builtin_memcpy(&f, &u, 4); return f;
}
__device__ __forceinline__ short f2s(float f) {
  bf16 h = __float2bfloat16(f); short s; __builtin_memcpy(&s, &h, 2); return s;
}

__device__ __forceinline__ void gload16(const void* g, void* l) {
  __builtin_amdgcn_global_load_lds(
      (const __attribute__((address_space(1))) void*)g,
      (__attribute__((address_space(3))) void*)l, 16, 0, 0);
}

static constexpr float QSCALE = 0.180336880111120426f;  // 0.125 * log2(e)

// --------- merged prep: weight cast f32->bf16  +  RMSNorm (one launch) ------
struct PrepArgs {
  const float* csrc[10]; bf16* cdst[10]; int cn[10];
  const float* nx[3]; const float* nw[3]; bf16* ny[3];
};
__global__ __launch_bounds__(256) void prep_kernel(PrepArgs a) {
  const int bx = blockIdx.x;
  if (bx < 10240) {
    const int y = bx >> 10;
    const int i = ((bx & 1023) * 256 + threadIdx.x) * 4;
    if (i >= a.cn[y]) return;
    const float4 v = *(const float4*)(a.csrc[y] + i);
    bf16* d = a.cdst[y] + i;
    d[0] = __float2bfloat16(v.x); d[1] = __float2bfloat16(v.y);
    d[2] = __float2bfloat16(v.z); d[3] = __float2bfloat16(v.w);
    return;
  }
  const int j = bx - 10240;
  int t, row;
  if (j < 2048) { t = 0; row = j; }
  else if (j < 10240) { t = 1; row = j - 2048; }
  else { t = 2; row = j - 10240; }
  const float* x = a.nx[t] + (size_t)row * DIM;
  const float4 v = *(const float4*)(x + threadIdx.x * 4);
  float ss = v.x*v.x + v.y*v.y + v.z*v.z + v.w*v.w;
  #pragma unroll
  for (int m = 32; m >= 1; m >>= 1) ss += __shfl_xor(ss, m);
  __shared__ float red[4];
  if ((threadIdx.x & 63) == 0) red[threadIdx.x >> 6] = ss;
  __syncthreads();
  ss = red[0] + red[1] + red[2] + red[3];
  const float sc = rsqrtf(ss * (1.0f / DIM) + 1.1920928955078125e-07f);
  const float4 w = *(const float4*)(a.nw[t] + threadIdx.x * 4);
  bf16* y = a.ny[t] + (size_t)row * DIM + threadIdx.x * 4;
  y[0] = __float2bfloat16(v.x * sc * w.x);
  y[1] = __float2bfloat16(v.y * sc * w.y);
  y[2] = __float2bfloat16(v.z * sc * w.z);
  y[3] = __float2bfloat16(v.w * sc * w.w);
}

// ============== 256x256 8-wave pipelined projection GEMM (r9 frozen) =========
struct PSlot { const bf16* A; const bf16* W; const float* bias;
               bf16* Cb; int epi; int sksh; };
struct PArgs { PSlot s[7]; };

__global__ __launch_bounds__(512, 2) void proj256(PArgs a) {
  __shared__ char lds[131072];   // [buf][A 32KB | B 32KB]
  const int tid = threadIdx.x, lane = tid & 63, wave = tid >> 6;
  const int m16 = lane & 15, g16 = lane >> 4;
  const int wm = wave >> 2, wn = wave & 3;

  const int i = (blockIdx.x & 7) * 64 + (blockIdx.x >> 3);
  int slot, rem;
  if (i < 384) { slot = i >> 7; rem = i & 127; }
  else { const int j = i - 384; slot = 3 + (j >> 5); rem = j & 31; }
  const PSlot S = a.s[slot];
  const int bn = rem & 3, bm = rem >> 2;

  const bf16* Ab = S.A + (size_t)bm * 256 * DIM;
  const bf16* Wb = S.W + (size_t)bn * 256 * DIM;

  auto stageAh = [&](int k0, int buf, int h) {
    #pragma unroll
    for (int q = 0; q < 2; ++q) {
      const int idx = (h * 2 + q) * 512 + tid;
      const int row = idx >> 3, g = (idx & 7) ^ (row & 7);
      gload16(Ab + (size_t)row * DIM + k0 + g * 8,
              &lds[buf * 65536 + (h * 2 + q) * 8192 + wave * 1024]);
    }
  };
  auto stageBfull = [&](int k0, int buf) {
    #pragma unroll
    for (int q = 0; q < 4; ++q) {
      const int idx = q * 512 + tid;
      const int row = idx >> 3, g = (idx & 7) ^ (row & 7);
      gload16(Wb + (size_t)row * DIM + k0 + g * 8,
              &lds[buf * 65536 + 32768 + q * 8192 + wave * 1024]);
    }
  };

  f32x4 acc[8][4];
  #pragma unroll
  for (int x = 0; x < 8; ++x)
    #pragma unroll
    for (int y = 0; y < 4; ++y)
      #pragma unroll
      for (int r = 0; r < 4; ++r) acc[x][y][r] = 0.0f;

  stageAh(0, 0, 0); stageAh(0, 0, 1);
  stageBfull(0, 0);
  stageBfull(64, 1);
  asm volatile("s_waitcnt vmcnt(4)" ::: "memory");
  SBAR();

  constexpr int NT = DIM / 64;   // 16
  for (int t = 0; t < NT; ++t) {
    const int buf = t & 1;
    const char* A0 = &lds[buf * 65536];
    const char* B0 = A0 + 32768;
    s16x8 af[4], bfk[4];

    // ---- P0: ds af(mh0,ks0) 4 + bf(ks0) 4; stage A(t+1) h0 ----
    #pragma unroll
    for (int mi = 0; mi < 4; ++mi) {
      const int row = wm * 128 + mi * 16 + m16;
      af[mi] = *(const s16x8*)(A0 + row * 128 + ((g16 ^ (m16 & 7)) * 16));
    }
    #pragma unroll
    for (int ni = 0; ni < 4; ++ni) {
      const int row = wn * 64 + ni * 16 + m16;
      bfk[ni] = *(const s16x8*)(B0 + row * 128 + ((g16 ^ (m16 & 7)) * 16));
    }
    if (t + 1 < NT) stageAh((t + 1) * 64, buf ^ 1, 0);
    SBAR();
    __builtin_amdgcn_s_setprio(1);
    #pragma unroll
    for (int mi = 0; mi < 4; ++mi)
      #pragma unroll
      for (int ni = 0; ni < 4; ++ni)
        acc[mi][ni] = MFMA32(af[mi], bfk[ni], acc[mi][ni]);
    __builtin_amdgcn_s_setprio(0);
    SBAR();

    // ---- P1: ds af(mh1,ks0) 4; stage A(t+1) h1 ----
    #pragma unroll
    for (int mi = 0; mi < 4; ++mi) {
      const int row = wm * 128 + 64 + mi * 16 + m16;
      af[mi] = *(const s16x8*)(A0 + row * 128 + ((g16 ^ (m16 & 7)) * 16));
    }
    if (t + 1 < NT) stageAh((t + 1) * 64, buf ^ 1, 1);
    SBAR();
    __builtin_amdgcn_s_setprio(1);
    #pragma unroll
    for (int mi = 0; mi < 4; ++mi)
      #pragma unroll
      for (int ni = 0; ni < 4; ++ni)
        acc[4 + mi][ni] = MFMA32(af[mi], bfk[ni], acc[4 + mi][ni]);
    __builtin_amdgcn_s_setprio(0);
    SBAR();

    // ---- P2: ds af(mh0,ks1) 4 + bf(ks1) 4 ----
    #pragma unroll
    for (int mi = 0; mi < 4; ++mi) {
      const int row = wm * 128 + mi * 16 + m16;
      af[mi] = *(const s16x8*)(A0 + row * 128 + (((4 + g16) ^ (m16 & 7)) * 16));
    }
    #pragma unroll
    for (int ni = 0; ni < 4; ++ni) {
      const int row = wn * 64 + ni * 16 + m16;
      bfk[ni] = *(const s16x8*)(B0 + row * 128 + (((4 + g16) ^ (m16 & 7)) * 16));
    }
    SBAR();
    __builtin_amdgcn_s_setprio(1);
    #pragma unroll
    for (int mi = 0; mi < 4; ++mi)
      #pragma unroll
      for (int ni = 0; ni < 4; ++ni)
        acc[mi][ni] = MFMA32(af[mi], bfk[ni], acc[mi][ni]);
    __builtin_amdgcn_s_setprio(0);
    SBAR();

    // ---- P3: ds af(mh1,ks1) 4; stage B(t+2) ----
    #pragma unroll
    for (int mi = 0; mi < 4; ++mi) {
      const int row = wm * 128 + 64 + mi * 16 + m16;
      af[mi] = *(const s16x8*)(A0 + row * 128 + (((4 + g16) ^ (m16 & 7)) * 16));
    }
    if (t + 2 < NT) stageBfull((t + 2) * 64, buf);
    SBAR();
    __builtin_amdgcn_s_setprio(1);
    #pragma unroll
    for (int mi = 0; mi < 4; ++mi)
      #pragma unroll
      for (int ni = 0; ni < 4; ++ni)
        acc[4 + mi][ni] = MFMA32(af[mi], bfk[ni], acc[4 + mi][ni]);
    __builtin_amdgcn_s_setprio(0);
    if (t < NT - 2)       { asm volatile("s_waitcnt vmcnt(4)" ::: "memory"); }
    else if (t == NT - 2) { asm volatile("s_waitcnt vmcnt(0)" ::: "memory"); }
    SBAR();
  }

  const int r0 = bm * 256 + wm * 128, c0 = bn * 256 + wn * 64;
  if (S.epi >= 3) {
    const float sc = (S.epi == 3) ? QSCALE : 1.0f;
    const int msk = (1 << S.sksh) - 1;
    #pragma unroll
    for (int ng = 0; ng < 4; ++ng) {
      const int col = c0 + ng * 16 + m16;
      const int hh = col >> 6, d = col & 63;
      const float bv = S.bias[col];
      #pragma unroll
      for (int mg = 0; mg < 8; ++mg) {
        const int rowb = r0 + mg * 16 + g16 * 4;
        #pragma unroll
        for (int r = 0; r < 4; ++r) {
          const int m = rowb + r;
          const int bb2 = m >> S.sksh, tok = m & msk;
          S.Cb[(((size_t)(bb2 * NH + hh) << S.sksh) + tok) * HD + d] =
              __float2bfloat16((acc[mg][ng][r] + bv) * sc);
        }
      }
    }
  } else {
    #pragma unroll
    for (int ng = 0; ng < 4; ++ng) {
      const int col = c0 + ng * 16 + m16;
      const float bv = S.bias[col];
      #pragma unroll
      for (int mg = 0; mg < 8; ++mg) {
        const int rowb = r0 + mg * 16 + g16 * 4;
        #pragma unroll
        for (int r = 0; r < 4; ++r) {
          float v = acc[mg][ng][r] + bv;
          const size_t idx = (size_t)(rowb + r) * DIM + col;
          if (S.epi == 1) { v = v / (1.0f + __expf(-v)); S.Cb[idx] = __float2bfloat16(v); }
          else            { S.Cb[idx] = __float2bfloat16(v); }
        }
      }
    }
  }
}

// -------- out-projection GEMM: 64x128 tile, 256 blocks (full CU fill) --------
struct GSlot { const bf16* A; const bf16* W; const float* bias;
               const float* resid; float* Cf; };
__global__ __launch_bounds__(256) void gemm_out(GSlot S) {
  constexpr int K = DIM;
  __shared__ alignas(16) char sA[4096];
  __shared__ alignas(16) char sB[8192];
  const int tid = threadIdx.x, lane = tid & 63, wave = tid >> 6;
  const int bm = blockIdx.x, bn = blockIdx.y;
  const int m16 = lane & 15, g16 = lane >> 4;

  f32x4 acc[4][2];
  #pragma unroll
  for (int i = 0; i < 4; ++i)
    #pragma unroll
    for (int j = 0; j < 2; ++j)
      #pragma unroll
      for (int r = 0; r < 4; ++r) acc[i][j][r] = 0.0f;

  const bf16* Ab = S.A + (size_t)bm * 64 * K;
  const bf16* Wb = S.W + (size_t)bn * 128 * K;

  for (int t = 0; t < K / 32; ++t) {
    const int k0 = t * 32;
    {
      const int row = tid >> 2, sg = (tid & 3) ^ (row & 3);
      gload16(Ab + (size_t)row * K + k0 + sg * 8, &sA[wave * 1024]);
    }
    #pragma unroll
    for (int p = 0; p < 2; ++p) {
      const int idx = p * 256 + tid;
      const int row = idx >> 2, sg = (idx & 3) ^ (row & 3);
      gload16(Wb + (size_t)row * K + k0 + sg * 8, &sB[p * 4096 + wave * 1024]);
    }
    __syncthreads();
    s16x8 af[4], bfr[2];
    #pragma unroll
    for (int mi = 0; mi < 4; ++mi) {
      const int row = mi * 16 + m16;
      af[mi] = *(const s16x8*)(&sA[row * 64 + (g16 ^ (m16 & 3)) * 16]);
    }
    #pragma unroll
    for (int ni = 0; ni < 2; ++ni) {
      const int row = wave * 32 + ni * 16 + m16;
      bfr[ni] = *(const s16x8*)(&sB[row * 64 + (g16 ^ (m16 & 3)) * 16]);
    }
    #pragma unroll
    for (int mi = 0; mi < 4; ++mi)
      #pragma unroll
      for (int ni = 0; ni < 2; ++ni)
        acc[mi][ni] = MFMA32(af[mi], bfr[ni], acc[mi][ni]);
    __syncthreads();
  }

  const int r0 = bm * 64, c0 = bn * 128 + wave * 32;
  #pragma unroll
  for (int ni = 0; ni < 2; ++ni) {
    const int col = c0 + ni * 16 + m16;
    const float bv = S.bias[col];
    #pragma unroll
    for (int mi = 0; mi < 4; ++mi) {
      const int rowb = r0 + mi * 16 + g16 * 4;
      #pragma unroll
      for (int r = 0; r < 4; ++r) {
        const size_t idx = (size_t)(rowb + r) * DIM + col;
        S.Cf[idx] = acc[mi][ni][r] + bv + S.resid[idx];
      }
    }
  }
}

// ---------------- merged gate GEMV (visual + text) ---------------------------
__global__ __launch_bounds__(256) void gate2_kernel(
    const bf16* __restrict__ g1v, const bf16* __restrict__ w2v,
    const float* __restrict__ b2v, float* __restrict__ gv,
    const bf16* __restrict__ g1t, const bf16* __restrict__ w2t,
    const float* __restrict__ b2t, float* __restrict__ gt)
{
  const int lane = threadIdx.x & 63, wave = threadIdx.x >> 6;
  int row = blockIdx.x * 4 + wave;
  const bf16* x; const bf16* w2; const float* b2; float* gate;
  if (row < BB * SKV) { x = g1v + (size_t)row * DIM; w2 = w2v; b2 = b2v; gate = gv + row; }
  else { row -= BB * SKV; x = g1t + (size_t)row * DIM; w2 = w2t; b2 = b2t; gate = gt + row; }
  float sum = 0.0f;
  #pragma unroll
  for (int c = 0; c < 2; ++c) {
    const int i0 = c * 512 + lane * 8;
    const s16x8 xv = *(const s16x8*)(x + i0);
    const s16x8 wv = *(const s16x8*)(w2 + i0);
    #pragma unroll
    for (int j = 0; j < 8; ++j) sum += b2f(xv[j]) * b2f(wv[j]);
  }
  #pragma unroll
  for (int m = 32; m >= 1; m >>= 1) sum += __shfl_xor(sum, m);
  if (lane == 0) *gate = 1.0f / (1.0f + __expf(-(sum + b2[0])));
}

// ------- merged V transpose + gate fold --------------------------------------
__global__ __launch_bounds__(256) void vtrans2_kernel(
    const bf16* __restrict__ Vv, const float* __restrict__ gv, bf16* __restrict__ VTv,
    const bf16* __restrict__ Vt, const float* __restrict__ gt, bf16* __restrict__ VTt)
{
  __shared__ alignas(16) short tile[64][72];
  int kt = blockIdx.x;
  const bf16* V; const float* gate; bf16* VT; int Sk;
  if (kt < SKV / 64) { V = Vv; gate = gv; VT = VTv; Sk = SKV; }
  else { kt -= SKV / 64; V = Vt; gate = gt; VT = VTt; Sk = SKT; }
  const int h = blockIdx.y, b = blockIdx.z;
  const int tid = threadIdx.x;
  #pragma unroll
  for (int i = 0; i < 2; ++i) {
    const int c = tid + i * 256;
    const int kr = c >> 3, d0 = (c & 7) * 8;
    const float g = gate[(size_t)b * Sk + kt * 64 + kr];
    const s16x8 v = *(const s16x8*)(V + ((size_t)(b*Sk + kt*64 + kr)*NH + h)*HD + d0);
    #pragma unroll
    for (int j = 0; j < 8; ++j) tile[kr][d0 + j] = f2s(b2f(v[j]) * g);
  }
  __syncthreads();
  #pragma unroll
  for (int i = 0; i < 2; ++i) {
    const int c = tid + i * 256;
    const int d = c >> 3, k0 = (c & 7) * 8;
    s16x8 v;
    #pragma unroll
    for (int j = 0; j < 8; ++j) v[j] = tile[k0 + j][d];
    *(s16x8*)(VT + ((size_t)(b*NH + h)*HD + d)*Sk + kt*64 + k0) = v;
  }
}

// ---------------- fused dual-context flash attention (r9 proven) -------------
// 512 threads: 4 q-subtiles (wq) x 2 kv-halves (hf); one staging round serves
// 64 q-rows. Double-buffered chunks (64 KB -> 2 blocks/CU co-resident; the
// cross-block overlap hides the per-chunk drain, m114). Per-context state in
// regs; both merges at the end through LDS scratch.
__global__ __launch_bounds__(512, 2) void attn_kernel(
    const bf16* __restrict__ Qh,
    const bf16* __restrict__ K1h, const bf16* __restrict__ VT1,
    const bf16* __restrict__ K2h, const bf16* __restrict__ VT2,
    bf16* __restrict__ Hout)
{
  __shared__ alignas(16) char sK[2][2][8192];   // [buf][half][64 tok x 64 d]
  __shared__ alignas(16) char sVT[2][2][8192];  // [buf][half][64 d x 64 kv]
  const int tid = threadIdx.x, lane = tid & 63, wave = tid >> 6;
  const int hb = blockIdx.x;
  const int h = hb & 15, b = hb >> 4;
  const int wq = wave & 3, hf = wave >> 2;
  const int q0 = blockIdx.y * 64 + wq * 16;
  const int m16 = lane & 15, g16 = lane >> 4;

  const bf16* qrow = Qh + ((size_t)(b*NH + h)*SQ + q0 + m16)*HD;
  const s16x8 qf0 = *(const s16x8*)(qrow + g16 * 8);
  const s16x8 qf1 = *(const s16x8*)(qrow + 32 + g16 * 8);

  const bf16* K1b  = K1h + (size_t)(b*NH + h) * SKV * HD;
  const bf16* K2b  = K2h + (size_t)(b*NH + h) * SKT * HD;
  const bf16* VT1b = VT1 + (size_t)(b*NH + h) * HD * SKV;
  const bf16* VT2b = VT2 + (size_t)(b*NH + h) * HD * SKT;

  constexpr int NC1 = SKV / 128, NC = NC1 + SKT / 128;  // 16 + 4

  auto stage = [&](int c, int buf) {
    const int ctx = (c >= NC1);
    const bf16* Kb  = ctx ? K2b  : K1b;
    const bf16* VTb = ctx ? VT2b : VT1b;
    const int Sk = ctx ? SKT : SKV;
    const int cc = ctx ? c - NC1 : c;
    const int b0 = cc * 64, b1 = (Sk >> 1) + cc * 64;
    const int r = tid >> 3, g = (tid & 7) ^ (r & 7);
    gload16(Kb  + (size_t)(b0 + r) * HD + g * 8, &sK[buf][0][wave * 1024]);
    gload16(Kb  + (size_t)(b1 + r) * HD + g * 8, &sK[buf][1][wave * 1024]);
    gload16(VTb + (size_t)r * Sk + b0 + g * 8,   &sVT[buf][0][wave * 1024]);
    gload16(VTb + (size_t)r * Sk + b1 + g * 8,   &sVT[buf][1][wave * 1024]);
  };

  f32x4 o[4], ov[4];
  float mx, l, mxv, lv;
  #pragma unroll
  for (int i = 0; i < 4; ++i)
    #pragma unroll
    for (int r = 0; r < 4; ++r) { o[i][r] = 0.0f; ov[i][r] = 0.0f; }
  mx = -1e30f; l = 0.0f; mxv = -1e30f; lv = 0.0f;

  auto chunk = [&](int buf) {
    const char* kbase = &sK[buf][hf][0];
    const char* vbase = &sVT[buf][hf][0];
    f32x4 s[4];
    #pragma unroll
    for (int nt = 0; nt < 4; ++nt) {
      const char* kr = kbase + (nt * 16 + m16) * 128;
      const s16x8 kf0 = *(const s16x8*)(kr + ((g16    ) ^ (m16 & 7)) * 16);
      const s16x8 kf1 = *(const s16x8*)(kr + ((4 + g16) ^ (m16 & 7)) * 16);
      f32x4 a2; a2[0] = 0; a2[1] = 0; a2[2] = 0; a2[3] = 0;
      a2 = MFMA32(kf0, qf0, a2);
      a2 = MFMA32(kf1, qf1, a2);
      s[nt] = a2;
    }
    float mc = s[0][0];
    #pragma unroll
    for (int nt = 0; nt < 4; ++nt)
      #pragma unroll
      for (int r = 0; r < 4; ++r) mc = fmaxf(mc, s[nt][r]);
    mc = fmaxf(mc, __shfl_xor(mc, 16));
    mc = fmaxf(mc, __shfl_xor(mc, 32));
    const float mnew = fmaxf(mx, mc);
    const float alpha = exp2f(mx - mnew);
    mx = mnew;
    float p[4][4]; float rs = 0.0f;
    #pragma unroll
    for (int nt = 0; nt < 4; ++nt)
      #pragma unroll
      for (int r = 0; r < 4; ++r) { p[nt][r] = exp2f(s[nt][r] - mnew); rs += p[nt][r]; }
    rs += __shfl_xor(rs, 16);
    rs += __shfl_xor(rs, 32);
    l = l * alpha + rs;
    float av[4];
    #pragma unroll
    for (int r = 0; r < 4; ++r) av[r] = __shfl(alpha, g16 * 4 + r);
    #pragma unroll
    for (int nd = 0; nd < 4; ++nd)
      #pragma unroll
      for (int r = 0; r < 4; ++r) o[nd][r] *= av[r];
    #pragma unroll
    for (int nt = 0; nt < 4; ++nt) {
      s16x4 pa;
      pa[0] = f2s(p[nt][0]); pa[1] = f2s(p[nt][1]);
      pa[2] = f2s(p[nt][2]); pa[3] = f2s(p[nt][3]);
      #pragma unroll
      for (int nd = 0; nd < 4; ++nd) {
        const int d = nd * 16 + m16;
        const int g = (nt * 2 + (g16 >> 1)) ^ (m16 & 7);
        const s16x4 vf = *(const s16x4*)(vbase + d * 128 + g * 16 + (g16 & 1) * 8);
        o[nd] = MFMA16(pa, vf, o[nd]);
      }
    }
  };

  stage(0, 0);
  asm volatile("s_waitcnt vmcnt(0)" ::: "memory");
  SBAR();

  int buf = 0;
  for (int c = 0; c < NC; ++c) {
    if (c + 1 < NC) stage(c + 1, buf ^ 1);
    chunk(buf);
    if (c == NC1 - 1) {   // save visual-context state, reset for text
      #pragma unroll
      for (int nd = 0; nd < 4; ++nd) ov[nd] = o[nd];
      mxv = mx; lv = l;
      #pragma unroll
      for (int nd = 0; nd < 4; ++nd)
        #pragma unroll
        for (int r = 0; r < 4; ++r) o[nd][r] = 0.0f;
      mx = -1e30f; l = 0.0f;
    }
    asm volatile("s_waitcnt vmcnt(0)" ::: "memory");
    SBAR();
    buf ^= 1;
  }

  // ---- final merges (LDS free now). scratch: mo[ctx][64 rows][64 d] -------
  float* mo = (float*)&sK[0][0][0];    // 2 x 16KB = 32KB
  float* ml = (float*)&sVT[0][0][0];   // [wq][ctx][2][16]
  if (hf) {
    #pragma unroll
    for (int nd = 0; nd < 4; ++nd)
      #pragma unroll
      for (int r = 0; r < 4; ++r) {
        const int rl = wq * 16 + g16 * 4 + r;
        mo[rl * 64 + nd * 16 + m16]        = ov[nd][r];
        mo[4096 + rl * 64 + nd * 16 + m16] = o[nd][r];
      }
    if (g16 == 0) {
      ml[(wq * 4 + 0) * 16 + m16] = mxv; ml[(wq * 4 + 1) * 16 + m16] = lv;
      ml[(wq * 4 + 2) * 16 + m16] = mx;  ml[(wq * 4 + 3) * 16 + m16] = l;
    }
  }
  __syncthreads();
  if (!hf) {
    float of[4][4];
    #pragma unroll
    for (int ctx = 0; ctx < 2; ++ctx) {
      const float mb = ml[(wq * 4 + ctx * 2 + 0) * 16 + m16];
      const float lb = ml[(wq * 4 + ctx * 2 + 1) * 16 + m16];
      const float ma = ctx ? mx : mxv;
      const float la = ctx ? l  : lv;
      const float ms = fmaxf(ma, mb);
      const float aA = exp2f(ma - ms), aB = exp2f(mb - ms);
      const float lt = la * aA + lb * aB;
      float aAv[4], aBv[4], ltv[4];
      #pragma unroll
      for (int r = 0; r < 4; ++r) {
        aAv[r] = __shfl(aA, g16 * 4 + r);
        aBv[r] = __shfl(aB, g16 * 4 + r);
        ltv[r] = __shfl(lt, g16 * 4 + r);
      }
      #pragma unroll
      for (int nd = 0; nd < 4; ++nd)
        #pragma unroll
        for (int r = 0; r < 4; ++r) {
          const int rl = wq * 16 + g16 * 4 + r;
          const float ob = mo[ctx * 4096 + rl * 64 + nd * 16 + m16];
          const float oa = ctx ? o[nd][r] : ov[nd][r];
          const float res = (oa * aAv[r] + ob * aBv[r]) / ltv[r];
          if (ctx == 0) of[nd][r] = res; else of[nd][r] += res;
        }
    }
    #pragma unroll
    for (int nd = 0; nd < 4; ++nd)
      #pragma unroll
      for (int r = 0; r < 4; ++r) {
        const int row = q0 + g16 * 4 + r;
        Hout[((size_t)(b*SQ + row)*NH + h)*HD + nd*16 + m16] =
            __float2bfloat16(of[nd][r]);
      }
  }
}

// ---------------- host launch ------------------------------------------------
extern "C" void kernel_launch(void* const* d_in, const int* in_sizes, int n_in,
                              void* d_out, int out_size, void* d_ws, size_t ws_size,
                              hipStream_t stream)
{
  const float* queries = (const float*)d_in[0];
  const float* ctx_v   = (const float*)d_in[1];
  const float* ctx_t   = (const float*)d_in[2];
  const float* w_nq = (const float*)d_in[3];
  const float* w_nv = (const float*)d_in[4];
  const float* w_nt = (const float*)d_in[5];
  const float* Wq   = (const float*)d_in[6];  const float* bq   = (const float*)d_in[7];
  const float* Wk_v = (const float*)d_in[8];  const float* bk_v = (const float*)d_in[9];
  const float* Wv_v = (const float*)d_in[10]; const float* bv_v = (const float*)d_in[11];
  const float* Wk_t = (const float*)d_in[12]; const float* bk_t = (const float*)d_in[13];
  const float* Wv_t = (const float*)d_in[14]; const float* bv_t = (const float*)d_in[15];
  const float* Wg1v = (const float*)d_in[16]; const float* bg1v = (const float*)d_in[17];
  const float* Wg2v = (const float*)d_in[18]; const float* bg2v = (const float*)d_in[19];
  const float* Wg1t = (const float*)d_in[20]; const float* bg1t = (const float*)d_in[21];
  const float* Wg2t = (const float*)d_in[22]; const float* bg2t = (const float*)d_in[23];
  const float* Wo   = (const float*)d_in[24]; const float* bo   = (const float*)d_in[25];

  char* ws = (char*)d_ws;
  size_t off = 0;
  auto alloc = [&](size_t n) { void* p = ws + off; off += (n + 255) & ~(size_t)255; return p; };

  const size_t MATB = (size_t)DIM * DIM * 2;
  bf16* WqB   = (bf16*)alloc(MATB);
  bf16* WkvB  = (bf16*)alloc(MATB);
  bf16* WvvB  = (bf16*)alloc(MATB);
  bf16* WktB  = (bf16*)alloc(MATB);
  bf16* WvtB  = (bf16*)alloc(MATB);
  bf16* Wg1vB = (bf16*)alloc(MATB);
  bf16* Wg1tB = (bf16*)alloc(MATB);
  bf16* WoB   = (bf16*)alloc(MATB);
  bf16* Wg2vB = (bf16*)alloc(2048);
  bf16* Wg2tB = (bf16*)alloc(2048);

  bf16* qn  = (bf16*)alloc((size_t)BB*SQ*DIM*2);
  bf16* cv  = (bf16*)alloc((size_t)BB*SKV*DIM*2);
  bf16* ct  = (bf16*)alloc((size_t)BB*SKT*DIM*2);
  bf16* qb  = (bf16*)alloc((size_t)BB*SQ*DIM*2);     // head-major, scaled
  bf16* kvB = (bf16*)alloc((size_t)BB*SKV*DIM*2);    // head-major
  bf16* ktB = (bf16*)alloc((size_t)BB*SKT*DIM*2);    // head-major
  bf16* vtV = (bf16*)alloc((size_t)BB*SKV*DIM*2);
  bf16* vtT = (bf16*)alloc((size_t)BB*SKT*DIM*2);
  bf16* vScrV = (bf16*)alloc((size_t)BB*SKV*DIM*2);
  bf16* vScrT = (bf16*)alloc((size_t)BB*SKT*DIM*2);
  bf16* g1V   = (bf16*)alloc((size_t)BB*SKV*DIM*2);
  bf16* g1T   = (bf16*)alloc((size_t)BB*SKT*DIM*2);
  float* gateV = (float*)alloc((size_t)BB*SKV*4);
  float* gateT = (float*)alloc((size_t)BB*SKT*4);
  bf16* hB  = (bf16*)alloc((size_t)BB*SQ*DIM*2);
  (void)ws_size; (void)n_in; (void)in_sizes; (void)out_size;

  // 1. weight casts + RMSNorms in ONE launch
  PrepArgs pr;
  const float* wsrc[10] = {Wq, Wk_v, Wv_v, Wk_t, Wv_t, Wg1v, Wg1t, Wo, Wg2v, Wg2t};
  bf16* wdst[10] = {WqB, WkvB, WvvB, WktB, WvtB, Wg1vB, Wg1tB, WoB, Wg2vB, Wg2tB};
  for (int i = 0; i < 10; ++i) {
    pr.csrc[i] = wsrc[i]; pr.cdst[i] = wdst[i];
    pr.cn[i] = (i < 8) ? DIM * DIM : DIM;
  }
  pr.nx[0] = queries; pr.nx[1] = ctx_v; pr.nx[2] = ctx_t;
  pr.nw[0] = w_nq;    pr.nw[1] = w_nv;  pr.nw[2] = w_nt;
  pr.ny[0] = qn;      pr.ny[1] = cv;    pr.ny[2] = ct;
  prep_kernel<<<dim3(10240 + 12288), 256, 0, stream>>>(pr);

  // 2. ALL 7 projections in one 256^2 pipelined dispatch
  PArgs pa;
  pa.s[0] = {cv, WkvB,  bk_v, kvB,   4, 11};   // K visual, head-major
  pa.s[1] = {cv, WvvB,  bv_v, vScrV, 0, 0};    // V visual
  pa.s[2] = {cv, Wg1vB, bg1v, g1V,   1, 0};    // G1 visual (silu)
  pa.s[3] = {qn, WqB,   bq,   qb,    3, 9};    // Q, head-major + scale
  pa.s[4] = {ct, WktB,  bk_t, ktB,   4, 9};    // K text, head-major
  pa.s[5] = {ct, WvtB,  bv_t, vScrT, 0, 0};    // V text
  pa.s[6] = {ct, Wg1tB, bg1t, g1T,   1, 0};    // G1 text (silu)
  proj256<<<dim3(512), 512, 0, stream>>>(pa);

  // 3. gates (both contexts) + gated V transpose (both contexts)
  gate2_kernel<<<dim3((BB*SKV + BB*SKT) / 4), 256, 0, stream>>>(
      g1V, Wg2vB, bg2v, gateV, g1T, Wg2tB, bg2t, gateT);
  vtrans2_kernel<<<dim3(SKV/64 + SKT/64, NH, BB), 256, 0, stream>>>(
      vScrV, gateV, vtV, vScrT, gateT, vtT);

  // 4. fused dual-context attention (512 threads, dbuf chunks, 2 blocks/CU)
  attn_kernel<<<dim3(NH*BB, SQ/64), 512, 0, stream>>>(qb, kvB, vtV, ktB, vtT, hB);

  // 5. output projection + residual (f32 out), 256 blocks
  GSlot go{hB, WoB, bo, queries, (float*)d_out};
  gemm_out<<<dim3(BB*SQ/64, 8), 256, 0, stream>>>(go);
}